// Round 3
// baseline (369.805 us; speedup 1.0000x reference)
//
#include <hip/hip_runtime.h>
#include <hip/hip_bf16.h>

#define BDIM 4
#define NSEQ 4096
#define DHEAD 128
#define SCALE 0.08838834764831845f

typedef __bf16 bf16x8 __attribute__((ext_vector_type(8)));
typedef float f32x4 __attribute__((ext_vector_type(4)));

__device__ __forceinline__ unsigned short f2bf(float f){
    return __builtin_bit_cast(unsigned short, (__bf16)f);
}
__device__ __forceinline__ unsigned long long pack4(float4 u){
    return (unsigned long long)f2bf(u.x)
         | ((unsigned long long)f2bf(u.y) << 16)
         | ((unsigned long long)f2bf(u.z) << 32)
         | ((unsigned long long)f2bf(u.w) << 48);
}

// ---------------------------------------------------------------------------
// Kernel 1: per-row softmax stats (m, l) with K-split=4.  (unchanged, verified)
// grid = B(4) * rowtiles(64) * ksplit(4) = 1024 blocks, 256 threads.
// Partials (m,l) per split land in attn output cols [2*ks, 2*ks+1].
// ---------------------------------------------------------------------------
extern "C" __global__ __launch_bounds__(256, 4)
void attn_stats(const float* __restrict__ K, const float* __restrict__ Q,
                float* __restrict__ out)
{
    __shared__ __align__(16) char Klds[64 * 256];

    const int bid = blockIdx.x;
    const int ks  = bid & 3;
    const int rt  = (bid >> 2) & 63;
    const int b   = bid >> 8;
    const int tid = threadIdx.x;
    const int lane = tid & 63;
    const int w    = tid >> 6;
    const int g    = lane >> 4;
    const int c    = lane & 15;
    const int rowbase = rt * 64;

    const float* qrow = Q + ((size_t)b * NSEQ + rowbase + w * 16 + c) * DHEAD;
    bf16x8 qf[4];
#pragma unroll
    for (int kk = 0; kk < 4; kk++) {
        const float4* p0 = (const float4*)(qrow + g * 8 + kk * 32);
        float4 u = p0[0], v = p0[1];
        bf16x8 t;
        t[0] = (__bf16)(u.x * SCALE); t[1] = (__bf16)(u.y * SCALE);
        t[2] = (__bf16)(u.z * SCALE); t[3] = (__bf16)(u.w * SCALE);
        t[4] = (__bf16)(v.x * SCALE); t[5] = (__bf16)(v.y * SCALE);
        t[6] = (__bf16)(v.z * SCALE); t[7] = (__bf16)(v.w * SCALE);
        qf[kk] = t;
    }

    float m[4], l[4];
#pragma unroll
    for (int r = 0; r < 4; r++) { m[r] = -1e30f; l[r] = 0.0f; }

    const int f  = tid & 31;
    const int r0 = tid >> 5;

    for (int kt = 0; kt < 16; kt++) {
        const float* ktile = K + ((size_t)b * NSEQ + ks * 1024 + kt * 64) * DHEAD;
#pragma unroll
        for (int i = 0; i < 8; i++) {
            int r = r0 + i * 8;
            float4 u = *(const float4*)(ktile + (size_t)r * DHEAD + f * 4);
            *(unsigned long long*)(Klds + r * 256 + ((f * 8) ^ ((r & 7) << 4))) = pack4(u);
        }
        __syncthreads();

        f32x4 acc[4];
#pragma unroll
        for (int n = 0; n < 4; n++) acc[n] = (f32x4){0.f, 0.f, 0.f, 0.f};
#pragma unroll
        for (int n = 0; n < 4; n++) {
            int row = n * 16 + c;
#pragma unroll
            for (int kk = 0; kk < 4; kk++) {
                bf16x8 kf = *(const bf16x8*)(Klds + row * 256 +
                                ((g * 16 + kk * 64) ^ ((row & 7) << 4)));
                acc[n] = __builtin_amdgcn_mfma_f32_16x16x32_bf16(qf[kk], kf, acc[n], 0, 0, 0);
            }
        }

#pragma unroll
        for (int r = 0; r < 4; r++) {
            float t = fmaxf(fmaxf(acc[0][r], acc[1][r]), fmaxf(acc[2][r], acc[3][r]));
            t = fmaxf(t, __shfl_xor(t, 1));
            t = fmaxf(t, __shfl_xor(t, 2));
            t = fmaxf(t, __shfl_xor(t, 4));
            t = fmaxf(t, __shfl_xor(t, 8));
            float mn = fmaxf(m[r], t);
            float sc = __expf(m[r] - mn);
            float ps = __expf(acc[0][r] - mn) + __expf(acc[1][r] - mn)
                     + __expf(acc[2][r] - mn) + __expf(acc[3][r] - mn);
            ps += __shfl_xor(ps, 1);
            ps += __shfl_xor(ps, 2);
            ps += __shfl_xor(ps, 4);
            ps += __shfl_xor(ps, 8);
            l[r] = l[r] * sc + ps;
            m[r] = mn;
        }
        __syncthreads();
    }

    if (c == 0) {
        float* attn = out + (size_t)BDIM * NSEQ * DHEAD;
#pragma unroll
        for (int r = 0; r < 4; r++) {
            size_t row = rowbase + w * 16 + g * 4 + r;
            float* p = attn + ((size_t)b * NSEQ + row) * NSEQ + ks * 2;
            p[0] = m[r];
            p[1] = l[r];
        }
    }
}

// ---------------------------------------------------------------------------
// Kernel 2: finalize.  32 q-rows per block, 4-way column split in-block.
// grid = B(4) * rowtiles(128) = 512 blocks, 512 threads (8 waves).
// wave w: rw = w&1 (16-row group), grp = w>>1 (1024-col quarter).
// LDS 72KB -> 2 blocks/CU (4 waves/SIMD).
// ---------------------------------------------------------------------------
extern "C" __global__ __launch_bounds__(512, 4)
void attn_final(const float* __restrict__ K, const float* __restrict__ Q,
                const float* __restrict__ V, float* __restrict__ out)
{
    __shared__ __align__(16) char LDS[73728];
    // [0,32768)      : K tiles, 4 grps x (32 keys x 128d bf16, swizzled) = 4 x 8KB
    // [32768,65536)  : Vt tiles, 4 grps x (128d x 32 keys bf16, swizzled) = 4 x 8KB
    // [65536,73728)  : P tiles, 8 waves x (16 q x 32 keys bf16, swizzled) = 8 x 1KB

    const int bid = blockIdx.x;
    const int rt  = bid & 127;
    const int b   = bid >> 7;
    const int tid = threadIdx.x;
    const int rowbase = rt * 32;
    const int lane = tid & 63;
    const int w    = tid >> 6;
    const int rw   = w & 1;
    const int grp  = w >> 1;
    const int g    = lane >> 4;
    const int c    = lane & 15;
    const int t    = tid & 127;   // index within the grp's 2 waves

    float* ctxOut = out;
    float* attn   = out + (size_t)BDIM * NSEQ * DHEAD;

    char* Klds  = LDS + grp * 8192;
    char* Vtlds = LDS + 32768 + grp * 8192;
    char* Plds  = LDS + 65536 + w * 1024;

    // ---- prologue: combine the 4 K-split partials -> C = M + log(L), per thread ----
    float Cst[4];
#pragma unroll
    for (int r = 0; r < 4; r++) {
        const float* prow = attn + ((size_t)b * NSEQ + rowbase + rw * 16 + g * 4 + r) * NSEQ;
        float4 p0 = *(const float4*)prow;
        float4 p1 = *(const float4*)(prow + 4);
        float M = fmaxf(fmaxf(p0.x, p0.z), fmaxf(p1.x, p1.z));
        float L = p0.y * __expf(p0.x - M) + p0.w * __expf(p0.z - M)
                + p1.y * __expf(p1.x - M) + p1.w * __expf(p1.z - M);
        Cst[r] = M + __logf(L);
    }

    // ---- Q fragments (scale folded) ----
    const float* qrow = Q + ((size_t)b * NSEQ + rowbase + rw * 16 + c) * DHEAD;
    bf16x8 qf[4];
#pragma unroll
    for (int kk = 0; kk < 4; kk++) {
        const float4* p0 = (const float4*)(qrow + g * 8 + kk * 32);
        float4 u = p0[0], v = p0[1];
        bf16x8 tt;
        tt[0] = (__bf16)(u.x * SCALE); tt[1] = (__bf16)(u.y * SCALE);
        tt[2] = (__bf16)(u.z * SCALE); tt[3] = (__bf16)(u.w * SCALE);
        tt[4] = (__bf16)(v.x * SCALE); tt[5] = (__bf16)(v.y * SCALE);
        tt[6] = (__bf16)(v.z * SCALE); tt[7] = (__bf16)(v.w * SCALE);
        qf[kk] = tt;
    }

    f32x4 ctx[8];
#pragma unroll
    for (int n2 = 0; n2 < 8; n2++) ctx[n2] = (f32x4){0.f, 0.f, 0.f, 0.f};

    __syncthreads();   // all prologue partial reads done before any attn store

    const int k0 = 4 * (t & 7);     // V staging: key base
    const int fK = t & 31;          // K staging: float4 idx 0..31 (full 128-d row)
    const int rK = t >> 5;          // K staging: row base 0..3

    for (int kt = 0; kt < 32; kt++) {
        const int col0 = grp * 1024 + kt * 32;
        const float* ktile = K + ((size_t)b * NSEQ + col0) * DHEAD;
        const float* vtile = V + ((size_t)b * NSEQ + col0) * DHEAD;

        // ---- stage K (32 keys x 128 d, bf16 rows of 256B, 16B-XOR swizzle) ----
        // 128 threads x 8 float4 = 1024 = 32 rows x 32 float4 (FULL row now)
#pragma unroll
        for (int i = 0; i < 8; i++) {
            int row = rK + i * 4;
            float4 u = *(const float4*)(ktile + (size_t)row * DHEAD + fK * 4);
            *(unsigned long long*)(Klds + row * 256 + ((fK * 8) ^ ((row & 7) << 4))) = pack4(u);
        }
        // ---- stage Vt (128 d-rows x 32 keys bf16, 64B rows, 16B-XOR swizzle) ----
#pragma unroll
        for (int i = 0; i < 4; i++) {
            int d0 = 2 * ((t >> 3) & 15) + 32 * i;
            float2 a0 = *(const float2*)(vtile + (size_t)(k0 + 0) * DHEAD + d0);
            float2 a1 = *(const float2*)(vtile + (size_t)(k0 + 1) * DHEAD + d0);
            float2 a2 = *(const float2*)(vtile + (size_t)(k0 + 2) * DHEAD + d0);
            float2 a3 = *(const float2*)(vtile + (size_t)(k0 + 3) * DHEAD + d0);
            unsigned long long r0 =
                (unsigned long long)f2bf(a0.x)
              | ((unsigned long long)f2bf(a1.x) << 16)
              | ((unsigned long long)f2bf(a2.x) << 32)
              | ((unsigned long long)f2bf(a3.x) << 48);
            unsigned long long r1 =
                (unsigned long long)f2bf(a0.y)
              | ((unsigned long long)f2bf(a1.y) << 16)
              | ((unsigned long long)f2bf(a2.y) << 32)
              | ((unsigned long long)f2bf(a3.y) << 48);
            int swz = ((d0 >> 1) & 3) << 4;
            *(unsigned long long*)(Vtlds + d0 * 64 + ((k0 * 2) ^ swz)) = r0;
            *(unsigned long long*)(Vtlds + (d0 + 1) * 64 + ((k0 * 2) ^ swz)) = r1;
        }
        __syncthreads();

        // ---- S = Q K^T (16 rows x 32 keys per wave) ----
        f32x4 sacc[2];
#pragma unroll
        for (int n = 0; n < 2; n++) sacc[n] = (f32x4){0.f, 0.f, 0.f, 0.f};
#pragma unroll
        for (int n = 0; n < 2; n++) {
            int row = n * 16 + c;
#pragma unroll
            for (int kk = 0; kk < 4; kk++) {
                bf16x8 kf = *(const bf16x8*)(Klds + row * 256 +
                                ((g * 16 + kk * 64) ^ ((row & 7) << 4)));
                sacc[n] = __builtin_amdgcn_mfma_f32_16x16x32_bf16(qf[kk], kf, sacc[n], 0, 0, 0);
            }
        }

        // ---- P = exp(s - C); store attn; stash bf16 P ----
        float pv[2][4];
#pragma unroll
        for (int n = 0; n < 2; n++)
#pragma unroll
            for (int r = 0; r < 4; r++)
                pv[n][r] = __expf(sacc[n][r] - Cst[r]);

#pragma unroll
        for (int r = 0; r < 4; r++) {
            float* arow = attn + ((size_t)b * NSEQ + rowbase + rw * 16 + g * 4 + r) * NSEQ
                        + col0 + c;
            arow[0]  = pv[0][r];
            arow[16] = pv[1][r];
        }

#pragma unroll
        for (int n = 0; n < 2; n++)
#pragma unroll
            for (int r = 0; r < 4; r++) {
                int row = g * 4 + r;
                *(unsigned short*)(Plds + row * 64 +
                    ((n * 32 + c * 2) ^ ((row & 3) << 4))) = f2bf(pv[n][r]);
            }
        asm volatile("s_waitcnt lgkmcnt(0)" ::: "memory");
        __builtin_amdgcn_sched_barrier(0);

        bf16x8 pf = *(const bf16x8*)(Plds + c * 64 + ((g * 16) ^ ((c & 3) << 4)));

        // ---- context += P V ----
#pragma unroll
        for (int n2 = 0; n2 < 8; n2++) {
            int d = n2 * 16 + c;
            bf16x8 vf = *(const bf16x8*)(Vtlds + d * 64 +
                            ((g * 16) ^ (((d >> 1) & 3) << 4)));
            ctx[n2] = __builtin_amdgcn_mfma_f32_16x16x32_bf16(pf, vf, ctx[n2], 0, 0, 0);
        }
        __syncthreads();
    }

    // ---- reduce context across the 4 column groups (LDS overlay), store ----
    float* red = (float*)LDS;   // 6 x 2048 floats = 48KB <= 72KB
    if (grp > 0) {
        float* dst = red + ((grp - 1) * 2 + rw) * 2048;
#pragma unroll
        for (int n2 = 0; n2 < 8; n2++)
#pragma unroll
            for (int r = 0; r < 4; r++)
                dst[(g * 4 + r) * 128 + n2 * 16 + c] = ctx[n2][r];
    }
    __syncthreads();
    if (grp == 0) {
#pragma unroll
        for (int n2 = 0; n2 < 8; n2++)
#pragma unroll
            for (int r = 0; r < 4; r++) {
                int idx = (g * 4 + r) * 128 + n2 * 16 + c;
                float s = ctx[n2][r]
                        + red[(0 * 2 + rw) * 2048 + idx]
                        + red[(1 * 2 + rw) * 2048 + idx]
                        + red[(2 * 2 + rw) * 2048 + idx];
                size_t row = rowbase + rw * 16 + g * 4 + r;
                ctxOut[((size_t)b * NSEQ + row) * DHEAD + n2 * 16 + c] = s;
            }
    }
}

extern "C" void kernel_launch(void* const* d_in, const int* in_sizes, int n_in,
                              void* d_out, int out_size, void* d_ws, size_t ws_size,
                              hipStream_t stream)
{
    const float* K = (const float*)d_in[0];   // "key"
    const float* Q = (const float*)d_in[1];   // "query"
    const float* V = (const float*)d_in[2];   // "value"
    float* out = (float*)d_out;

    attn_stats<<<dim3(4 * 64 * 4), dim3(256), 0, stream>>>(K, Q, out);
    attn_final<<<dim3(4 * 128), dim3(512), 0, stream>>>(K, Q, V, out);
}

// Round 4
// 212.158 us; speedup vs baseline: 1.7431x; 1.7431x over previous
//
#include <hip/hip_runtime.h>
#include <hip/hip_bf16.h>

#define BDIM 4
#define NSEQ 4096
#define DHEAD 128
#define SCALE 0.08838834764831845f

typedef __bf16 bf16x8 __attribute__((ext_vector_type(8)));
typedef float f32x4 __attribute__((ext_vector_type(4)));

__device__ __forceinline__ unsigned short f2bf(float f){
    return __builtin_bit_cast(unsigned short, (__bf16)f);
}
__device__ __forceinline__ unsigned long long pack4(float4 u){
    return (unsigned long long)f2bf(u.x)
         | ((unsigned long long)f2bf(u.y) << 16)
         | ((unsigned long long)f2bf(u.z) << 32)
         | ((unsigned long long)f2bf(u.w) << 48);
}

// ---------------------------------------------------------------------------
// Kernel 1: per-row softmax stats (m, l) with K-split=4.  (unchanged, verified)
// ---------------------------------------------------------------------------
extern "C" __global__ __launch_bounds__(256, 4)
void attn_stats(const float* __restrict__ K, const float* __restrict__ Q,
                float* __restrict__ out)
{
    __shared__ __align__(16) char Klds[64 * 256];

    const int bid = blockIdx.x;
    const int ks  = bid & 3;
    const int rt  = (bid >> 2) & 63;
    const int b   = bid >> 8;
    const int tid = threadIdx.x;
    const int lane = tid & 63;
    const int w    = tid >> 6;
    const int g    = lane >> 4;
    const int c    = lane & 15;
    const int rowbase = rt * 64;

    const float* qrow = Q + ((size_t)b * NSEQ + rowbase + w * 16 + c) * DHEAD;
    bf16x8 qf[4];
#pragma unroll
    for (int kk = 0; kk < 4; kk++) {
        const float4* p0 = (const float4*)(qrow + g * 8 + kk * 32);
        float4 u = p0[0], v = p0[1];
        bf16x8 t;
        t[0] = (__bf16)(u.x * SCALE); t[1] = (__bf16)(u.y * SCALE);
        t[2] = (__bf16)(u.z * SCALE); t[3] = (__bf16)(u.w * SCALE);
        t[4] = (__bf16)(v.x * SCALE); t[5] = (__bf16)(v.y * SCALE);
        t[6] = (__bf16)(v.z * SCALE); t[7] = (__bf16)(v.w * SCALE);
        qf[kk] = t;
    }

    float m[4], l[4];
#pragma unroll
    for (int r = 0; r < 4; r++) { m[r] = -1e30f; l[r] = 0.0f; }

    const int f  = tid & 31;
    const int r0 = tid >> 5;

    for (int kt = 0; kt < 16; kt++) {
        const float* ktile = K + ((size_t)b * NSEQ + ks * 1024 + kt * 64) * DHEAD;
#pragma unroll
        for (int i = 0; i < 8; i++) {
            int r = r0 + i * 8;
            float4 u = *(const float4*)(ktile + (size_t)r * DHEAD + f * 4);
            *(unsigned long long*)(Klds + r * 256 + ((f * 8) ^ ((r & 7) << 4))) = pack4(u);
        }
        __syncthreads();

        f32x4 acc[4];
#pragma unroll
        for (int n = 0; n < 4; n++) acc[n] = (f32x4){0.f, 0.f, 0.f, 0.f};
#pragma unroll
        for (int n = 0; n < 4; n++) {
            int row = n * 16 + c;
#pragma unroll
            for (int kk = 0; kk < 4; kk++) {
                bf16x8 kf = *(const bf16x8*)(Klds + row * 256 +
                                ((g * 16 + kk * 64) ^ ((row & 7) << 4)));
                acc[n] = __builtin_amdgcn_mfma_f32_16x16x32_bf16(qf[kk], kf, acc[n], 0, 0, 0);
            }
        }

#pragma unroll
        for (int r = 0; r < 4; r++) {
            float t = fmaxf(fmaxf(acc[0][r], acc[1][r]), fmaxf(acc[2][r], acc[3][r]));
            t = fmaxf(t, __shfl_xor(t, 1));
            t = fmaxf(t, __shfl_xor(t, 2));
            t = fmaxf(t, __shfl_xor(t, 4));
            t = fmaxf(t, __shfl_xor(t, 8));
            float mn = fmaxf(m[r], t);
            float sc = __expf(m[r] - mn);
            float ps = __expf(acc[0][r] - mn) + __expf(acc[1][r] - mn)
                     + __expf(acc[2][r] - mn) + __expf(acc[3][r] - mn);
            ps += __shfl_xor(ps, 1);
            ps += __shfl_xor(ps, 2);
            ps += __shfl_xor(ps, 4);
            ps += __shfl_xor(ps, 8);
            l[r] = l[r] * sc + ps;
            m[r] = mn;
        }
        __syncthreads();
    }

    if (c == 0) {
        float* attn = out + (size_t)BDIM * NSEQ * DHEAD;
#pragma unroll
        for (int r = 0; r < 4; r++) {
            size_t row = rowbase + w * 16 + g * 4 + r;
            float* p = attn + ((size_t)b * NSEQ + row) * NSEQ + ks * 2;
            p[0] = m[r];
            p[1] = l[r];
        }
    }
}

// ---------------------------------------------------------------------------
// Kernel 2: finalize. 64 q-rows/block, 2 col-groups, 64-key tiles, 32 iters.
// grid = B(4) * rowtiles(64) = 256 blocks, 512 threads (8 waves).
// wave w: rw = w&3 (16-row group), grp = w>>2 (2048-col half).
// Swapped MFMA: S^T = mfma(K, Q) so each lane's 4 acc regs = 4 consecutive
// keys for one q-row -> float4 attn stores, scalar per-lane C.
// T14: global->reg prefetch of tile t+1 under tile-t compute; raw s_barrier
// (no vmcnt drain).
// ---------------------------------------------------------------------------
extern "C" __global__ __launch_bounds__(512, 2)
void attn_final(const float* __restrict__ K, const float* __restrict__ Q,
                const float* __restrict__ V, float* __restrict__ out)
{
    __shared__ __align__(16) char LDS[81920];
    // [0,32768)      : K tiles, 2 grps x (64 keys x 128d bf16, 256B rows, XOR (row&7)<<4)
    // [32768,65536)  : Vt tiles, 2 grps x (128d x 64 keys bf16, 128B rows, XOR (d&7)<<4)
    // [65536,81920)  : P tiles, 8 waves x (16 q x 64 keys bf16, 128B rows, XOR (q&7)<<4)

    const int bid = blockIdx.x;
    const int rt  = bid & 63;
    const int b   = bid >> 6;
    const int tid = threadIdx.x;
    const int rowbase = rt * 64;
    const int lane = tid & 63;
    const int w    = tid >> 6;
    const int rw   = w & 3;
    const int grp  = w >> 2;
    const int g    = lane >> 4;
    const int c    = lane & 15;
    const int t    = tid & 255;   // index within the grp's 4 waves

    float* ctxOut = out;
    float* attn   = out + (size_t)BDIM * NSEQ * DHEAD;

    char* Klds  = LDS + grp * 16384;
    char* Vtlds = LDS + 32768 + grp * 16384;
    char* Plds  = LDS + 65536 + w * 2048;

    // ---- prologue: combine 4 K-split partials -> C = M + log(L) for q = c-row ----
    float Cq;
    {
        const float* prow = attn + ((size_t)b * NSEQ + rowbase + rw * 16 + c) * NSEQ;
        float4 p0 = *(const float4*)prow;
        float4 p1 = *(const float4*)(prow + 4);
        float M = fmaxf(fmaxf(p0.x, p0.z), fmaxf(p1.x, p1.z));
        float L = p0.y * __expf(p0.x - M) + p0.w * __expf(p0.z - M)
                + p1.y * __expf(p1.x - M) + p1.w * __expf(p1.z - M);
        Cq = M + __logf(L);
    }

    // ---- Q fragments (B operand, q = c; scale folded) ----
    const float* qrow = Q + ((size_t)b * NSEQ + rowbase + rw * 16 + c) * DHEAD;
    bf16x8 qf[4];
#pragma unroll
    for (int kk = 0; kk < 4; kk++) {
        const float4* p0 = (const float4*)(qrow + g * 8 + kk * 32);
        float4 u = p0[0], v = p0[1];
        bf16x8 tt;
        tt[0] = (__bf16)(u.x * SCALE); tt[1] = (__bf16)(u.y * SCALE);
        tt[2] = (__bf16)(u.z * SCALE); tt[3] = (__bf16)(u.w * SCALE);
        tt[4] = (__bf16)(v.x * SCALE); tt[5] = (__bf16)(v.y * SCALE);
        tt[6] = (__bf16)(v.z * SCALE); tt[7] = (__bf16)(v.w * SCALE);
        qf[kk] = tt;
    }

    f32x4 ctx[8];
#pragma unroll
    for (int n2 = 0; n2 < 8; n2++) ctx[n2] = (f32x4){0.f, 0.f, 0.f, 0.f};

    // ---- staging index map (256 threads per col-group) ----
    const int fK = t & 31;       // K: float4 idx in d (full 128-d row)
    const int rK = t >> 5;       // K: row base 0..7
    const int dq = t & 15;       // V: d-pair base (coalesced: consecutive t -> consecutive d)
    const int kb = t >> 4;       // V: key quad 0..15
    const int k0 = kb * 4;
    const int d0 = dq * 2;

    const float* kbase = K + ((size_t)b * NSEQ + grp * 2048) * DHEAD;
    const float* vbase = V + ((size_t)b * NSEQ + grp * 2048) * DHEAD;

    float4 kreg[8];
    float2 vreg[4][4];

    // ---- prefetch tile 0 into registers ----
#pragma unroll
    for (int i = 0; i < 8; i++)
        kreg[i] = *(const float4*)(kbase + (size_t)(rK + i * 8) * DHEAD + fK * 4);
#pragma unroll
    for (int i = 0; i < 4; i++)
#pragma unroll
        for (int j = 0; j < 4; j++)
            vreg[i][j] = *(const float2*)(vbase + (size_t)(k0 + j) * DHEAD + d0 + 32 * i);

    for (int kt = 0; kt < 32; kt++) {
        // All waves' LDS reads of the previous tile were consumed by MFMA
        // operands before reaching here -> raw barrier is safe and does NOT
        // drain the outstanding prefetch vmcnt.
        __builtin_amdgcn_s_barrier();

        // ---- publish staged regs -> LDS (bf16, swizzled) ----
#pragma unroll
        for (int i = 0; i < 8; i++) {
            int row = rK + i * 8;
            *(unsigned long long*)(Klds + row * 256 + ((fK * 8) ^ ((row & 7) << 4))) = pack4(kreg[i]);
        }
#pragma unroll
        for (int i = 0; i < 4; i++) {
            int d = d0 + 32 * i;
            unsigned long long rr0 =
                (unsigned long long)f2bf(vreg[i][0].x)
              | ((unsigned long long)f2bf(vreg[i][1].x) << 16)
              | ((unsigned long long)f2bf(vreg[i][2].x) << 32)
              | ((unsigned long long)f2bf(vreg[i][3].x) << 48);
            unsigned long long rr1 =
                (unsigned long long)f2bf(vreg[i][0].y)
              | ((unsigned long long)f2bf(vreg[i][1].y) << 16)
              | ((unsigned long long)f2bf(vreg[i][2].y) << 32)
              | ((unsigned long long)f2bf(vreg[i][3].y) << 48);
            int swz = (d & 7) << 4;            // d even
            *(unsigned long long*)(Vtlds + d * 128 + ((k0 * 2) ^ swz)) = rr0;
            *(unsigned long long*)(Vtlds + (d + 1) * 128 + ((k0 * 2) ^ (swz + 16))) = rr1;
        }
        asm volatile("s_waitcnt lgkmcnt(0)" ::: "memory");
        __builtin_amdgcn_s_barrier();

        // ---- prefetch tile kt+1 (wraps harmlessly on last iter) ----
        {
            int kn = (kt + 1) & 31;
            const float* kp = kbase + (size_t)kn * 64 * DHEAD;
            const float* vp = vbase + (size_t)kn * 64 * DHEAD;
#pragma unroll
            for (int i = 0; i < 8; i++)
                kreg[i] = *(const float4*)(kp + (size_t)(rK + i * 8) * DHEAD + fK * 4);
#pragma unroll
            for (int i = 0; i < 4; i++)
#pragma unroll
                for (int j = 0; j < 4; j++)
                    vreg[i][j] = *(const float2*)(vp + (size_t)(k0 + j) * DHEAD + d0 + 32 * i);
        }

        // ---- S^T = K Q^T : 4 tiles of (16 keys x 16 q) per wave ----
        f32x4 sacc[4];
#pragma unroll
        for (int nt = 0; nt < 4; nt++) sacc[nt] = (f32x4){0.f, 0.f, 0.f, 0.f};
        __builtin_amdgcn_s_setprio(1);
#pragma unroll
        for (int nt = 0; nt < 4; nt++) {
            int row = nt * 16 + c;          // key row (A operand m-index = c)
#pragma unroll
            for (int kk = 0; kk < 4; kk++) {
                bf16x8 kf = *(const bf16x8*)(Klds + row * 256 +
                                ((g * 16 + kk * 64) ^ ((row & 7) << 4)));
                sacc[nt] = __builtin_amdgcn_mfma_f32_16x16x32_bf16(kf, qf[kk], sacc[nt], 0, 0, 0);
            }
        }
        __builtin_amdgcn_s_setprio(0);

        // ---- P = exp(s - C): float4 attn store + bf16 P stash per tile ----
        const int col0 = grp * 2048 + kt * 64;
        float* arow = attn + ((size_t)b * NSEQ + rowbase + rw * 16 + c) * NSEQ + col0;
#pragma unroll
        for (int nt = 0; nt < 4; nt++) {
            float4 pv;
            pv.x = __expf(sacc[nt][0] - Cq);
            pv.y = __expf(sacc[nt][1] - Cq);
            pv.z = __expf(sacc[nt][2] - Cq);
            pv.w = __expf(sacc[nt][3] - Cq);
            *(float4*)(arow + nt * 16 + g * 4) = pv;   // keys nt*16+g*4 .. +3
            *(unsigned long long*)(Plds + c * 128 +
                ((nt * 32 + g * 8) ^ ((c & 7) << 4))) = pack4(pv);
        }
        asm volatile("s_waitcnt lgkmcnt(0)" ::: "memory");
        __builtin_amdgcn_sched_barrier(0);

        bf16x8 pf[2];
#pragma unroll
        for (int kk = 0; kk < 2; kk++)
            pf[kk] = *(const bf16x8*)(Plds + c * 128 +
                        ((kk * 64 + g * 16) ^ ((c & 7) << 4)));

        // ---- context += P V ----
        __builtin_amdgcn_s_setprio(1);
#pragma unroll
        for (int n2 = 0; n2 < 8; n2++) {
            int d = n2 * 16 + c;
#pragma unroll
            for (int kk = 0; kk < 2; kk++) {
                bf16x8 vf = *(const bf16x8*)(Vtlds + d * 128 +
                                ((kk * 64 + g * 16) ^ ((d & 7) << 4)));
                ctx[n2] = __builtin_amdgcn_mfma_f32_16x16x32_bf16(pf[kk], vf, ctx[n2], 0, 0, 0);
            }
        }
        __builtin_amdgcn_s_setprio(0);
    }

    __syncthreads();   // full drain before LDS overlay reuse

    // ---- reduce context across the 2 column groups, store ----
    float* red = (float*)LDS;   // 4 rw x 16 rows x 128 f32 = 32KB overlay
    if (grp == 1) {
#pragma unroll
        for (int n2 = 0; n2 < 8; n2++)
#pragma unroll
            for (int r = 0; r < 4; r++)
                red[(rw * 16 + g * 4 + r) * 128 + n2 * 16 + c] = ctx[n2][r];
    }
    __syncthreads();
    if (grp == 0) {
#pragma unroll
        for (int n2 = 0; n2 < 8; n2++)
#pragma unroll
            for (int r = 0; r < 4; r++) {
                size_t row = rowbase + rw * 16 + g * 4 + r;
                ctxOut[((size_t)b * NSEQ + row) * DHEAD + n2 * 16 + c] =
                    ctx[n2][r] + red[(rw * 16 + g * 4 + r) * 128 + n2 * 16 + c];
            }
    }
}

extern "C" void kernel_launch(void* const* d_in, const int* in_sizes, int n_in,
                              void* d_out, int out_size, void* d_ws, size_t ws_size,
                              hipStream_t stream)
{
    const float* K = (const float*)d_in[0];   // "key"
    const float* Q = (const float*)d_in[1];   // "query"
    const float* V = (const float*)d_in[2];   // "value"
    float* out = (float*)d_out;

    attn_stats<<<dim3(4 * 64 * 4), dim3(256), 0, stream>>>(K, Q, out);
    attn_final<<<dim3(4 * 64), dim3(512), 0, stream>>>(K, Q, V, out);
}

// Round 5
// 154.183 us; speedup vs baseline: 2.3985x; 1.3760x over previous
//
#include <hip/hip_runtime.h>
#include <hip/hip_bf16.h>

#define BDIM 4
#define NSEQ 4096
#define DHEAD 128
#define SCALE 0.08838834764831845f

typedef __bf16 bf16x8 __attribute__((ext_vector_type(8)));
typedef float f32x4 __attribute__((ext_vector_type(4)));

__device__ __forceinline__ unsigned short f2bf(float f){
    return __builtin_bit_cast(unsigned short, (__bf16)f);
}
__device__ __forceinline__ unsigned long long pack4(float4 u){
    return (unsigned long long)f2bf(u.x)
         | ((unsigned long long)f2bf(u.y) << 16)
         | ((unsigned long long)f2bf(u.z) << 32)
         | ((unsigned long long)f2bf(u.w) << 48);
}
__device__ __forceinline__ void gload_lds16(const void* g, void* l){
    __builtin_amdgcn_global_load_lds(
        (const __attribute__((address_space(1))) unsigned int*)g,
        (__attribute__((address_space(3))) unsigned int*)l, 16, 0, 0);
}

// ---------------------------------------------------------------------------
// Kernel 1: per-row softmax stats (m, l), K-split=4. Partials land at
// pbase + row*pstride + ks*2  (ws in repack path, attn cols 0..7 in fallback).
// ---------------------------------------------------------------------------
extern "C" __global__ __launch_bounds__(256, 4)
void attn_stats(const float* __restrict__ K, const float* __restrict__ Q,
                float* __restrict__ pbase, int pstride)
{
    __shared__ __align__(16) char Klds[64 * 256];

    const int bid = blockIdx.x;
    const int ks  = bid & 3;
    const int rt  = (bid >> 2) & 63;
    const int b   = bid >> 8;
    const int tid = threadIdx.x;
    const int lane = tid & 63;
    const int w    = tid >> 6;
    const int g    = lane >> 4;
    const int c    = lane & 15;
    const int rowbase = rt * 64;

    const float* qrow = Q + ((size_t)b * NSEQ + rowbase + w * 16 + c) * DHEAD;
    bf16x8 qf[4];
#pragma unroll
    for (int kk = 0; kk < 4; kk++) {
        const float4* p0 = (const float4*)(qrow + g * 8 + kk * 32);
        float4 u = p0[0], v = p0[1];
        bf16x8 t;
        t[0] = (__bf16)(u.x * SCALE); t[1] = (__bf16)(u.y * SCALE);
        t[2] = (__bf16)(u.z * SCALE); t[3] = (__bf16)(u.w * SCALE);
        t[4] = (__bf16)(v.x * SCALE); t[5] = (__bf16)(v.y * SCALE);
        t[6] = (__bf16)(v.z * SCALE); t[7] = (__bf16)(v.w * SCALE);
        qf[kk] = t;
    }

    float m[4], l[4];
#pragma unroll
    for (int r = 0; r < 4; r++) { m[r] = -1e30f; l[r] = 0.0f; }

    const int f  = tid & 31;
    const int r0 = tid >> 5;

    for (int kt = 0; kt < 16; kt++) {
        const float* ktile = K + ((size_t)b * NSEQ + ks * 1024 + kt * 64) * DHEAD;
#pragma unroll
        for (int i = 0; i < 8; i++) {
            int r = r0 + i * 8;
            float4 u = *(const float4*)(ktile + (size_t)r * DHEAD + f * 4);
            *(unsigned long long*)(Klds + r * 256 + ((f * 8) ^ ((r & 7) << 4))) = pack4(u);
        }
        __syncthreads();

        f32x4 acc[4];
#pragma unroll
        for (int n = 0; n < 4; n++) acc[n] = (f32x4){0.f, 0.f, 0.f, 0.f};
#pragma unroll
        for (int n = 0; n < 4; n++) {
            int row = n * 16 + c;
#pragma unroll
            for (int kk = 0; kk < 4; kk++) {
                bf16x8 kf = *(const bf16x8*)(Klds + row * 256 +
                                ((g * 16 + kk * 64) ^ ((row & 7) << 4)));
                acc[n] = __builtin_amdgcn_mfma_f32_16x16x32_bf16(qf[kk], kf, acc[n], 0, 0, 0);
            }
        }

#pragma unroll
        for (int r = 0; r < 4; r++) {
            float t = fmaxf(fmaxf(acc[0][r], acc[1][r]), fmaxf(acc[2][r], acc[3][r]));
            t = fmaxf(t, __shfl_xor(t, 1));
            t = fmaxf(t, __shfl_xor(t, 2));
            t = fmaxf(t, __shfl_xor(t, 4));
            t = fmaxf(t, __shfl_xor(t, 8));
            float mn = fmaxf(m[r], t);
            float sc = __expf(m[r] - mn);
            float ps = __expf(acc[0][r] - mn) + __expf(acc[1][r] - mn)
                     + __expf(acc[2][r] - mn) + __expf(acc[3][r] - mn);
            ps += __shfl_xor(ps, 1);
            ps += __shfl_xor(ps, 2);
            ps += __shfl_xor(ps, 4);
            ps += __shfl_xor(ps, 8);
            l[r] = l[r] * sc + ps;
            m[r] = mn;
        }
        __syncthreads();
    }

    if (c == 0) {
#pragma unroll
        for (int r = 0; r < 4; r++) {
            size_t row = rowbase + w * 16 + g * 4 + r;
            float* p = pbase + ((size_t)b * NSEQ + row) * pstride + ks * 2;
            p[0] = m[r];
            p[1] = l[r];
        }
    }
}

// ---------------------------------------------------------------------------
// Kernel R: repack K -> bf16 swizzled LDS-tile images, V -> transposed bf16
// swizzled images, in d_ws.  ws layout: [0,4MB) Kpack, [4MB,8MB) Vtpack.
// Tile (b,T): 64 keys x 128 d.  Image formats match attn_final2's ds_reads:
//   K:  row(64) x 256B,  16B-unit j holds d-floats (j^(row&7))*8..+8
//   Vt: d(128) x 128B,   16B-unit jj holds keys ((jj^(d&7))*8..+8) at dim d
// ---------------------------------------------------------------------------
extern "C" __global__ __launch_bounds__(256, 4)
void repack(const float* __restrict__ K, const float* __restrict__ V,
            char* __restrict__ ws)
{
    const int bid = blockIdx.x;     // 4b * 64T
    const int T = bid & 63;
    const int b = bid >> 6;
    const int tid = threadIdx.x;

    char* Kp = ws + ((size_t)(b * 64 + T) << 14);
    char* Vp = ws + (4u << 20) + ((size_t)(b * 64 + T) << 14);
    const float* Ks = K + ((size_t)b * NSEQ + T * 64) * DHEAD;
    const float* Vs = V + ((size_t)b * NSEQ + T * 64) * DHEAD;

    // K: 1024 16B units
#pragma unroll
    for (int i = 0; i < 4; i++) {
        int u = tid + 256 * i;
        int row = u >> 4, j = u & 15;
        const float* s = Ks + (size_t)row * DHEAD + (j ^ (row & 7)) * 8;
        float4 a = *(const float4*)s;
        float4 bq = *(const float4*)(s + 4);
        ulonglong2 wv;
        wv.x = pack4(a);
        wv.y = pack4(bq);
        *(ulonglong2*)(Kp + row * 256 + j * 16) = wv;
    }
    // Vt: 1024 16B units (gathered transpose; V read exactly once)
#pragma unroll
    for (int i = 0; i < 4; i++) {
        int u = tid + 256 * i;
        int d = u >> 3, jj = u & 7;
        int k0 = (jj ^ (d & 7)) * 8;
        float v0 = Vs[(size_t)(k0 + 0) * DHEAD + d];
        float v1 = Vs[(size_t)(k0 + 1) * DHEAD + d];
        float v2 = Vs[(size_t)(k0 + 2) * DHEAD + d];
        float v3 = Vs[(size_t)(k0 + 3) * DHEAD + d];
        float v4 = Vs[(size_t)(k0 + 4) * DHEAD + d];
        float v5 = Vs[(size_t)(k0 + 5) * DHEAD + d];
        float v6 = Vs[(size_t)(k0 + 6) * DHEAD + d];
        float v7 = Vs[(size_t)(k0 + 7) * DHEAD + d];
        ulonglong2 wv;
        wv.x = (unsigned long long)f2bf(v0)
             | ((unsigned long long)f2bf(v1) << 16)
             | ((unsigned long long)f2bf(v2) << 32)
             | ((unsigned long long)f2bf(v3) << 48);
        wv.y = (unsigned long long)f2bf(v4)
             | ((unsigned long long)f2bf(v5) << 16)
             | ((unsigned long long)f2bf(v6) << 32)
             | ((unsigned long long)f2bf(v7) << 48);
        *(ulonglong2*)(Vp + d * 128 + jj * 16) = wv;
    }
}

// ---------------------------------------------------------------------------
// Kernel 2 (repack path): 64 q-rows x 2048 keys per block; grid 512 = 2/CU.
// 8 waves: rw=w&3 (16-row group), kh=w>>2 (32-key half of each 64-key tile).
// Staging = global_load_lds of pre-swizzled images, double-buffered,
// counted vmcnt (T3/T4).  ctx partials combined via atomicAdd (zeroed ctx).
// ---------------------------------------------------------------------------
extern "C" __global__ __launch_bounds__(512, 4)
void attn_final2(const char* __restrict__ ws, const float* __restrict__ Q,
                 float* __restrict__ out)
{
    __shared__ __align__(16) char LDS[73728];
    // [0,32K): K bufs (2 x 16KB)  [32K,64K): Vt bufs (2 x 16KB)  [64K,72K): P (4 rw x 2KB)

    const int bid = blockIdx.x;     // b(4) x rt(64) x ks(2)
    const int ks  = bid & 1;
    const int rt  = (bid >> 1) & 63;
    const int b   = bid >> 7;
    const int tid = threadIdx.x;
    const int rowbase = rt * 64;
    const int lane = tid & 63;
    const int w    = tid >> 6;
    const int rw   = w & 3;
    const int kh   = w >> 2;
    const int g    = lane >> 4;
    const int c    = lane & 15;

    float* ctxOut = out;
    float* attn   = out + (size_t)BDIM * NSEQ * DHEAD;
    const float* pbase = (const float*)(ws + (8u << 20));

    char* Plds = LDS + 65536 + rw * 2048;

    // ---- prologue: combine K-split partials -> C for q-row (rw*16+c) ----
    float Cq;
    {
        const float* prow = pbase + ((size_t)b * NSEQ + rowbase + rw * 16 + c) * 8;
        float4 p0 = *(const float4*)prow;
        float4 p1 = *(const float4*)(prow + 4);
        float M = fmaxf(fmaxf(p0.x, p0.z), fmaxf(p1.x, p1.z));
        float L = p0.y * __expf(p0.x - M) + p0.w * __expf(p0.z - M)
                + p1.y * __expf(p1.x - M) + p1.w * __expf(p1.z - M);
        Cq = M + __logf(L);
    }

    // ---- Q fragments (scale folded), q = rw*16 + c ----
    const float* qrow = Q + ((size_t)b * NSEQ + rowbase + rw * 16 + c) * DHEAD;
    bf16x8 qf[4];
#pragma unroll
    for (int kk = 0; kk < 4; kk++) {
        const float4* p0 = (const float4*)(qrow + g * 8 + kk * 32);
        float4 u = p0[0], v = p0[1];
        bf16x8 tt;
        tt[0] = (__bf16)(u.x * SCALE); tt[1] = (__bf16)(u.y * SCALE);
        tt[2] = (__bf16)(u.z * SCALE); tt[3] = (__bf16)(u.w * SCALE);
        tt[4] = (__bf16)(v.x * SCALE); tt[5] = (__bf16)(v.y * SCALE);
        tt[6] = (__bf16)(v.z * SCALE); tt[7] = (__bf16)(v.w * SCALE);
        qf[kk] = tt;
    }

    f32x4 ctx[8];
#pragma unroll
    for (int n2 = 0; n2 < 8; n2++) ctx[n2] = (f32x4){0.f, 0.f, 0.f, 0.f};

    const char* Kg  = ws + ((size_t)(b * 64 + ks * 32) << 14);
    const char* Vg  = ws + (4u << 20) + ((size_t)(b * 64 + ks * 32) << 14);
    const int o0 = tid * 16, o1 = (tid + 512) * 16;

    // prologue loads: tile 0 -> buf 0
    gload_lds16(Kg + o0, LDS + o0);
    gload_lds16(Kg + o1, LDS + o1);
    gload_lds16(Vg + o0, LDS + 32768 + o0);
    gload_lds16(Vg + o1, LDS + 32768 + o1);

    for (int kt = 0; kt < 32; kt++) {
        __builtin_amdgcn_s_barrier();              // everyone done reading buf (kt+1)&1
        __builtin_amdgcn_sched_barrier(0);
        if (kt < 31) {                             // issue tile kt+1 -> other buf
            const char* kg = Kg + ((size_t)(kt + 1) << 14);
            const char* vg = Vg + ((size_t)(kt + 1) << 14);
            char* kb = LDS + (((kt + 1) & 1) << 14);
            char* vb = LDS + 32768 + (((kt + 1) & 1) << 14);
            gload_lds16(kg + o0, kb + o0);
            gload_lds16(kg + o1, kb + o1);
            gload_lds16(vg + o0, vb + o0);
            gload_lds16(vg + o1, vb + o1);
            asm volatile("s_waitcnt vmcnt(4)" ::: "memory");   // own tile-kt loads done
        } else {
            asm volatile("s_waitcnt vmcnt(0)" ::: "memory");
        }
        __builtin_amdgcn_s_barrier();              // all waves' tile-kt loads done
        __builtin_amdgcn_sched_barrier(0);

        char* Kl = LDS + ((kt & 1) << 14);
        char* Vl = LDS + 32768 + ((kt & 1) << 14);

        // ---- S^T = K Q^T : 2 tiles of (16 keys x 16 q) per wave ----
        f32x4 sacc[2];
#pragma unroll
        for (int nt = 0; nt < 2; nt++) sacc[nt] = (f32x4){0.f, 0.f, 0.f, 0.f};
        __builtin_amdgcn_s_setprio(1);
#pragma unroll
        for (int nt = 0; nt < 2; nt++) {
            int row = kh * 32 + nt * 16 + c;
#pragma unroll
            for (int kk = 0; kk < 4; kk++) {
                bf16x8 kf = *(const bf16x8*)(Kl + row * 256 +
                                ((g * 16 + kk * 64) ^ ((row & 7) << 4)));
                sacc[nt] = __builtin_amdgcn_mfma_f32_16x16x32_bf16(kf, qf[kk], sacc[nt], 0, 0, 0);
            }
        }
        __builtin_amdgcn_s_setprio(0);

        // ---- P = exp(s - C): float4 attn stores + bf16 P stash ----
        const int col0 = ks * 2048 + kt * 64;
        float* arow = attn + ((size_t)b * NSEQ + rowbase + rw * 16 + c) * NSEQ
                    + col0 + kh * 32;
#pragma unroll
        for (int nt = 0; nt < 2; nt++) {
            float4 pv;
            pv.x = __expf(sacc[nt][0] - Cq);
            pv.y = __expf(sacc[nt][1] - Cq);
            pv.z = __expf(sacc[nt][2] - Cq);
            pv.w = __expf(sacc[nt][3] - Cq);
            *(float4*)(arow + nt * 16 + g * 4) = pv;
            *(unsigned long long*)(Plds + c * 128 +
                ((kh * 64 + nt * 32 + g * 8) ^ ((c & 7) << 4))) = pack4(pv);
        }
        asm volatile("s_waitcnt lgkmcnt(0)" ::: "memory");
        __builtin_amdgcn_sched_barrier(0);

        bf16x8 pf = *(const bf16x8*)(Plds + c * 128 +
                        ((kh * 64 + g * 16) ^ ((c & 7) << 4)));

        // ---- ctx += P V  (own 32-key half) ----
        __builtin_amdgcn_s_setprio(1);
#pragma unroll
        for (int n2 = 0; n2 < 8; n2++) {
            int d = n2 * 16 + c;
            bf16x8 vf = *(const bf16x8*)(Vl + d * 128 +
                            ((kh * 64 + g * 16) ^ ((d & 7) << 4)));
            ctx[n2] = __builtin_amdgcn_mfma_f32_16x16x32_bf16(pf, vf, ctx[n2], 0, 0, 0);
        }
        __builtin_amdgcn_s_setprio(0);
    }

    __syncthreads();   // full drain before LDS overlay

    // ---- reduce kh halves in LDS, then atomicAdd ks-partials to ctx ----
    float* red = (float*)LDS;    // 64 rows x 128 d = 32KB
    if (kh == 1) {
#pragma unroll
        for (int n2 = 0; n2 < 8; n2++)
#pragma unroll
            for (int r = 0; r < 4; r++)
                red[(rw * 16 + g * 4 + r) * 128 + n2 * 16 + c] = ctx[n2][r];
    }
    __syncthreads();
    if (kh == 0) {
#pragma unroll
        for (int n2 = 0; n2 < 8; n2++)
#pragma unroll
            for (int r = 0; r < 4; r++) {
                size_t row = rowbase + rw * 16 + g * 4 + r;
                float s = ctx[n2][r] + red[(rw * 16 + g * 4 + r) * 128 + n2 * 16 + c];
                atomicAdd(&ctxOut[((size_t)b * NSEQ + row) * DHEAD + n2 * 16 + c], s);
            }
    }
}

// ---------------------------------------------------------------------------
// Fallback finalize (proven R4 kernel, reads partials from attn cols 0..7).
// ---------------------------------------------------------------------------
extern "C" __global__ __launch_bounds__(512, 2)
void attn_final_fb(const float* __restrict__ K, const float* __restrict__ Q,
                   const float* __restrict__ V, float* __restrict__ out)
{
    __shared__ __align__(16) char LDS[81920];

    const int bid = blockIdx.x;
    const int rt  = bid & 63;
    const int b   = bid >> 6;
    const int tid = threadIdx.x;
    const int rowbase = rt * 64;
    const int lane = tid & 63;
    const int w    = tid >> 6;
    const int rw   = w & 3;
    const int grp  = w >> 2;
    const int g    = lane >> 4;
    const int c    = lane & 15;
    const int t    = tid & 255;

    float* ctxOut = out;
    float* attn   = out + (size_t)BDIM * NSEQ * DHEAD;

    char* Klds  = LDS + grp * 16384;
    char* Vtlds = LDS + 32768 + grp * 16384;
    char* Plds  = LDS + 65536 + w * 2048;

    float Cq;
    {
        const float* prow = attn + ((size_t)b * NSEQ + rowbase + rw * 16 + c) * NSEQ;
        float4 p0 = *(const float4*)prow;
        float4 p1 = *(const float4*)(prow + 4);
        float M = fmaxf(fmaxf(p0.x, p0.z), fmaxf(p1.x, p1.z));
        float L = p0.y * __expf(p0.x - M) + p0.w * __expf(p0.z - M)
                + p1.y * __expf(p1.x - M) + p1.w * __expf(p1.z - M);
        Cq = M + __logf(L);
    }

    const float* qrow = Q + ((size_t)b * NSEQ + rowbase + rw * 16 + c) * DHEAD;
    bf16x8 qf[4];
#pragma unroll
    for (int kk = 0; kk < 4; kk++) {
        const float4* p0 = (const float4*)(qrow + g * 8 + kk * 32);
        float4 u = p0[0], v = p0[1];
        bf16x8 tt;
        tt[0] = (__bf16)(u.x * SCALE); tt[1] = (__bf16)(u.y * SCALE);
        tt[2] = (__bf16)(u.z * SCALE); tt[3] = (__bf16)(u.w * SCALE);
        tt[4] = (__bf16)(v.x * SCALE); tt[5] = (__bf16)(v.y * SCALE);
        tt[6] = (__bf16)(v.z * SCALE); tt[7] = (__bf16)(v.w * SCALE);
        qf[kk] = tt;
    }

    f32x4 ctx[8];
#pragma unroll
    for (int n2 = 0; n2 < 8; n2++) ctx[n2] = (f32x4){0.f, 0.f, 0.f, 0.f};

    __syncthreads();

    const int fK = t & 31;
    const int rK = t >> 5;
    const int dq = t & 15;
    const int kb = t >> 4;
    const int k0 = kb * 4;
    const int d0 = dq * 2;

    const float* kbase = K + ((size_t)b * NSEQ + grp * 2048) * DHEAD;
    const float* vbase = V + ((size_t)b * NSEQ + grp * 2048) * DHEAD;

    float4 kreg[8];
    float2 vreg[4][4];

#pragma unroll
    for (int i = 0; i < 8; i++)
        kreg[i] = *(const float4*)(kbase + (size_t)(rK + i * 8) * DHEAD + fK * 4);
#pragma unroll
    for (int i = 0; i < 4; i++)
#pragma unroll
        for (int j = 0; j < 4; j++)
            vreg[i][j] = *(const float2*)(vbase + (size_t)(k0 + j) * DHEAD + d0 + 32 * i);

    for (int kt = 0; kt < 32; kt++) {
        __builtin_amdgcn_s_barrier();

#pragma unroll
        for (int i = 0; i < 8; i++) {
            int row = rK + i * 8;
            *(unsigned long long*)(Klds + row * 256 + ((fK * 8) ^ ((row & 7) << 4))) = pack4(kreg[i]);
        }
#pragma unroll
        for (int i = 0; i < 4; i++) {
            int d = d0 + 32 * i;
            unsigned long long rr0 =
                (unsigned long long)f2bf(vreg[i][0].x)
              | ((unsigned long long)f2bf(vreg[i][1].x) << 16)
              | ((unsigned long long)f2bf(vreg[i][2].x) << 32)
              | ((unsigned long long)f2bf(vreg[i][3].x) << 48);
            unsigned long long rr1 =
                (unsigned long long)f2bf(vreg[i][0].y)
              | ((unsigned long long)f2bf(vreg[i][1].y) << 16)
              | ((unsigned long long)f2bf(vreg[i][2].y) << 32)
              | ((unsigned long long)f2bf(vreg[i][3].y) << 48);
            int swz = (d & 7) << 4;
            *(unsigned long long*)(Vtlds + d * 128 + ((k0 * 2) ^ swz)) = rr0;
            *(unsigned long long*)(Vtlds + (d + 1) * 128 + ((k0 * 2) ^ (swz + 16))) = rr1;
        }
        asm volatile("s_waitcnt lgkmcnt(0)" ::: "memory");
        __builtin_amdgcn_s_barrier();

        {
            int kn = (kt + 1) & 31;
            const float* kp = kbase + (size_t)kn * 64 * DHEAD;
            const float* vp = vbase + (size_t)kn * 64 * DHEAD;
#pragma unroll
            for (int i = 0; i < 8; i++)
                kreg[i] = *(const float4*)(kp + (size_t)(rK + i * 8) * DHEAD + fK * 4);
#pragma unroll
            for (int i = 0; i < 4; i++)
#pragma unroll
                for (int j = 0; j < 4; j++)
                    vreg[i][j] = *(const float2*)(vp + (size_t)(k0 + j) * DHEAD + d0 + 32 * i);
        }

        f32x4 sacc[4];
#pragma unroll
        for (int nt = 0; nt < 4; nt++) sacc[nt] = (f32x4){0.f, 0.f, 0.f, 0.f};
        __builtin_amdgcn_s_setprio(1);
#pragma unroll
        for (int nt = 0; nt < 4; nt++) {
            int row = nt * 16 + c;
#pragma unroll
            for (int kk = 0; kk < 4; kk++) {
                bf16x8 kf = *(const bf16x8*)(Klds + row * 256 +
                                ((g * 16 + kk * 64) ^ ((row & 7) << 4)));
                sacc[nt] = __builtin_amdgcn_mfma_f32_16x16x32_bf16(kf, qf[kk], sacc[nt], 0, 0, 0);
            }
        }
        __builtin_amdgcn_s_setprio(0);

        const int col0 = grp * 2048 + kt * 64;
        float* arow = attn + ((size_t)b * NSEQ + rowbase + rw * 16 + c) * NSEQ + col0;
#pragma unroll
        for (int nt = 0; nt < 4; nt++) {
            float4 pv;
            pv.x = __expf(sacc[nt][0] - Cq);
            pv.y = __expf(sacc[nt][1] - Cq);
            pv.z = __expf(sacc[nt][2] - Cq);
            pv.w = __expf(sacc[nt][3] - Cq);
            *(float4*)(arow + nt * 16 + g * 4) = pv;
            *(unsigned long long*)(Plds + c * 128 +
                ((nt * 32 + g * 8) ^ ((c & 7) << 4))) = pack4(pv);
        }
        asm volatile("s_waitcnt lgkmcnt(0)" ::: "memory");
        __builtin_amdgcn_sched_barrier(0);

        bf16x8 pf[2];
#pragma unroll
        for (int kk = 0; kk < 2; kk++)
            pf[kk] = *(const bf16x8*)(Plds + c * 128 +
                        ((kk * 64 + g * 16) ^ ((c & 7) << 4)));

        __builtin_amdgcn_s_setprio(1);
#pragma unroll
        for (int n2 = 0; n2 < 8; n2++) {
            int d = n2 * 16 + c;
#pragma unroll
            for (int kk = 0; kk < 2; kk++) {
                bf16x8 vf = *(const bf16x8*)(Vtlds + d * 128 +
                                ((kk * 64 + g * 16) ^ ((d & 7) << 4)));
                ctx[n2] = __builtin_amdgcn_mfma_f32_16x16x32_bf16(pf[kk], vf, ctx[n2], 0, 0, 0);
            }
        }
        __builtin_amdgcn_s_setprio(0);
    }

    __syncthreads();

    float* red = (float*)LDS;
    if (grp == 1) {
#pragma unroll
        for (int n2 = 0; n2 < 8; n2++)
#pragma unroll
            for (int r = 0; r < 4; r++)
                red[(rw * 16 + g * 4 + r) * 128 + n2 * 16 + c] = ctx[n2][r];
    }
    __syncthreads();
    if (grp == 0) {
#pragma unroll
        for (int n2 = 0; n2 < 8; n2++)
#pragma unroll
            for (int r = 0; r < 4; r++) {
                size_t row = rowbase + rw * 16 + g * 4 + r;
                ctxOut[((size_t)b * NSEQ + row) * DHEAD + n2 * 16 + c] =
                    ctx[n2][r] + red[(rw * 16 + g * 4 + r) * 128 + n2 * 16 + c];
            }
    }
}

extern "C" void kernel_launch(void* const* d_in, const int* in_sizes, int n_in,
                              void* d_out, int out_size, void* d_ws, size_t ws_size,
                              hipStream_t stream)
{
    const float* K = (const float*)d_in[0];   // "key"
    const float* Q = (const float*)d_in[1];   // "query"
    const float* V = (const float*)d_in[2];   // "value"
    float* out  = (float*)d_out;
    float* attn = out + (size_t)BDIM * NSEQ * DHEAD;

    const size_t need = (8u << 20) + (size_t)BDIM * NSEQ * 8 * sizeof(float);
    if (ws_size >= need) {
        char* ws = (char*)d_ws;
        float* pb = (float*)(ws + (8u << 20));
        hipMemsetAsync(out, 0, (size_t)BDIM * NSEQ * DHEAD * sizeof(float), stream);
        attn_stats<<<dim3(4 * 64 * 4), dim3(256), 0, stream>>>(K, Q, pb, 8);
        repack<<<dim3(4 * 64), dim3(256), 0, stream>>>(K, V, ws);
        attn_final2<<<dim3(4 * 64 * 2), dim3(512), 0, stream>>>(ws, Q, out);
    } else {
        attn_stats<<<dim3(4 * 64 * 4), dim3(256), 0, stream>>>(K, Q, attn, NSEQ);
        attn_final_fb<<<dim3(4 * 64), dim3(512), 0, stream>>>(K, Q, V, out);
    }
}